// Round 2
// baseline (252.405 us; speedup 1.0000x reference)
//
#include <hip/hip_runtime.h>
#include <math.h>

#define CCH 256
#define CROP 7

__global__ __launch_bounds__(64) void roi_align_kernel(
    const float4* __restrict__ boxes,   // (B*N) boxes as float4; reference reads
                                        // cols as [row1, col1, row2, col2]
    const float* __restrict__ f0,
    const float* __restrict__ f1,
    const float* __restrict__ f2,
    const float* __restrict__ f3,
    const float* __restrict__ f4,
    const int*  __restrict__ image_shape,
    float* __restrict__ out,
    int N)                              // boxes per batch image
{
    const int cell = blockIdx.x;        // 0..48
    const int bn   = blockIdx.y;        // 0..B*N-1
    const int c4   = threadIdx.x;       // 0..63 -> channels c4*4..c4*4+3
    const int iy   = cell / CROP;
    const int ix   = cell % CROP;
    const int b    = bn / N;

    const float4 box = boxes[bn];
    // Reference: y1,x1,y2,x2 = boxes[:,0],boxes[:,1],boxes[:,2],boxes[:,3]
    const float ry1 = box.x;   // row start  (col 0)
    const float cx1 = box.y;   // col start  (col 1)
    const float ry2 = box.z;   // row end    (col 2)
    const float cx2 = box.w;   // col end    (col 3)

    // level: h = col3-col1, w = col2-col0 (product symmetric in the swap)
    const float h = cx2 - cx1;
    const float w = ry2 - ry1;

    const float area  = (float)(image_shape[0] * image_shape[1]);
    const float canon = 56.0f / sqrtf(area);
    const float lvlf  = log2f(sqrtf(h * w) / canon);
    int lvl = (int)rintf(lvlf);         // half-to-even, matches jnp.round
    lvl = lvl < 0 ? 0 : (lvl > 4 ? 4 : lvl);

    const float* f; int s;
    if      (lvl == 0) { f = f0; s = 256; }
    else if (lvl == 1) { f = f1; s = 128; }
    else if (lvl == 2) { f = f2; s = 64;  }
    else if (lvl == 3) { f = f3; s = 32;  }
    else               { f = f4; s = 16;  }

    const float Hf = (float)(s - 1);
    const float Wf = Hf;

    // ys from (ry1, ry2); xs from (cx1, cx2) — same op order as reference
    const float ystep = (ry2 - ry1) * Hf / 6.0f;
    const float xstep = (cx2 - cx1) * Wf / 6.0f;
    const float ys = ry1 * Hf + (float)iy * ystep;
    const float xs = cx1 * Wf + (float)ix * xstep;

    const float y0f = floorf(ys);
    const float x0f = floorf(xs);
    const float ly = ys - y0f;
    const float lx = xs - x0f;

    const int y0  = (int)fminf(fmaxf(y0f,        0.0f), Hf);
    const int y1i = (int)fminf(fmaxf(y0f + 1.0f, 0.0f), Hf);
    const int x0  = (int)fminf(fmaxf(x0f,        0.0f), Wf);
    const int x1i = (int)fminf(fmaxf(x0f + 1.0f, 0.0f), Wf);

    const bool ok = (ys >= 0.0f) && (ys <= Hf) && (xs >= 0.0f) && (xs <= Wf);

    const size_t img  = (size_t)b * s * s * CCH;
    const size_t o00  = img + ((size_t)y0  * s + x0 ) * CCH;
    const size_t o01  = img + ((size_t)y0  * s + x1i) * CCH;
    const size_t o10  = img + ((size_t)y1i * s + x0 ) * CCH;
    const size_t o11  = img + ((size_t)y1i * s + x1i) * CCH;

    const float4 v00 = *((const float4*)(f + o00) + c4);
    const float4 v01 = *((const float4*)(f + o01) + c4);
    const float4 v10 = *((const float4*)(f + o10) + c4);
    const float4 v11 = *((const float4*)(f + o11) + c4);

    float4 val;
    {
        float tx = v00.x + lx * (v01.x - v00.x);
        float bx = v10.x + lx * (v11.x - v10.x);
        val.x = tx + ly * (bx - tx);
        float ty = v00.y + lx * (v01.y - v00.y);
        float by = v10.y + lx * (v11.y - v10.y);
        val.y = ty + ly * (by - ty);
        float tz = v00.z + lx * (v01.z - v00.z);
        float bz = v10.z + lx * (v11.z - v10.z);
        val.z = tz + ly * (bz - tz);
        float tw = v00.w + lx * (v01.w - v00.w);
        float bw = v10.w + lx * (v11.w - v10.w);
        val.w = tw + ly * (bw - tw);
    }
    if (!ok) { val.x = 0.0f; val.y = 0.0f; val.z = 0.0f; val.w = 0.0f; }

    float4* optr = (float4*)(out + ((size_t)bn * (CROP * CROP) + cell) * CCH) + c4;
    *optr = val;
}

extern "C" void kernel_launch(void* const* d_in, const int* in_sizes, int n_in,
                              void* d_out, int out_size, void* d_ws, size_t ws_size,
                              hipStream_t stream) {
    const float4* boxes = (const float4*)d_in[0];
    const float*  f0    = (const float*)d_in[1];
    const float*  f1    = (const float*)d_in[2];
    const float*  f2    = (const float*)d_in[3];
    const float*  f3    = (const float*)d_in[4];
    const float*  f4    = (const float*)d_in[5];
    const int*    ishp  = (const int*)d_in[6];
    float*        out   = (float*)d_out;

    const int BN = in_sizes[0] / 4;                    // B*N
    const int B  = in_sizes[1] / (256 * 256 * 256);    // from feat0
    const int N  = BN / B;

    dim3 grid(CROP * CROP, BN);
    roi_align_kernel<<<grid, 64, 0, stream>>>(boxes, f0, f1, f2, f3, f4, ishp, out, N);
}